// Round 1
// baseline (383.190 us; speedup 1.0000x reference)
//
#include <hip/hip_runtime.h>

#define IN_DIM 29
#define XDIM 32
#define OUT_DIM 64
#define BN_EPS 1e-5f

// ---------------------------------------------------------------------------
// Kernel 0: pack features||node into 32-float rows (aligned gather target)
// xpack[n][0..28] = features[n][0..28]; xpack[n][29..31] = node[n][0..2]
// ---------------------------------------------------------------------------
__global__ void pack_kernel(const float* __restrict__ features,
                            const float* __restrict__ node,
                            float* __restrict__ xpack, int n_nodes) {
    int t = blockIdx.x * blockDim.x + threadIdx.x;
    int total = n_nodes * XDIM;
    if (t >= total) return;
    int n = t >> 5, i = t & 31;
    float v = (i < IN_DIM) ? features[n * IN_DIM + i] : node[n * 3 + (i - IN_DIM)];
    xpack[t] = v;
}

// ---------------------------------------------------------------------------
// Kernel 1: init output (as int keys) to encode(-inf) sentinel = INT_MIN
// ---------------------------------------------------------------------------
__global__ void init_kernel(int4* __restrict__ out, int total4) {
    int t = blockIdx.x * blockDim.x + threadIdx.x;
    if (t < total4) {
        out[t] = make_int4(INT_MIN, INT_MIN, INT_MIN, INT_MIN);
    }
}

// ---------------------------------------------------------------------------
// Kernel 2: main edge kernel. One wave per contiguous edge chunk.
// All 64 lanes process the same edge; lane = output dim.
// Lane l holds weight row l (the GEMV column for its dim) in 32 VGPRs.
// msg = (W x - mean) * (gamma/sqrt(var+eps)) + beta, then ordered-int
// atomicMax into out[dst*64 + lane].
// ---------------------------------------------------------------------------
template <bool PACKED>
__global__ __launch_bounds__(256) void edge_kernel(
    const int* __restrict__ edges,
    const float* __restrict__ xpack,      // PACKED path
    const float* __restrict__ features,   // fallback path
    const float* __restrict__ node,       // fallback path
    const float* __restrict__ weight,
    const float* __restrict__ gamma,
    const float* __restrict__ beta,
    const float* __restrict__ rmean,
    const float* __restrict__ rvar,
    int* __restrict__ out,
    int n_edges, int edges_per_wave)
{
    const int lane = threadIdx.x & 63;
    const int wave = __builtin_amdgcn_readfirstlane(
        (int)((blockIdx.x * blockDim.x + threadIdx.x) >> 6));
    int e0 = wave * edges_per_wave;
    int e1 = e0 + edges_per_wave;
    if (e1 > n_edges) e1 = n_edges;

    // Per-lane weight column (weight is [64][32] row-major; lane l needs row l)
    float w[XDIM];
    const float4* wp = (const float4*)(weight + lane * XDIM);
#pragma unroll
    for (int q = 0; q < 8; ++q) {
        float4 v = wp[q];
        w[4*q+0] = v.x; w[4*q+1] = v.y; w[4*q+2] = v.z; w[4*q+3] = v.w;
    }
    const float inv_std = gamma[lane] * __frsqrt_rn(rvar[lane] + BN_EPS);
    const float bprime  = beta[lane] - rmean[lane] * inv_std;

    for (int e = e0; e < e1; ++e) {
        const int dst = __builtin_amdgcn_readfirstlane(edges[2*e + 0]);
        const int src = __builtin_amdgcn_readfirstlane(edges[2*e + 1]);

        float x[XDIM];
        if (PACKED) {
            const float4* xs = (const float4*)(xpack + src * XDIM);
#pragma unroll
            for (int q = 0; q < 8; ++q) {
                float4 v = xs[q];
                x[4*q+0] = v.x; x[4*q+1] = v.y; x[4*q+2] = v.z; x[4*q+3] = v.w;
            }
            // dst node tail: xpack[dst][28..31] = {feat28, node0, node1, node2}
            float4 dt = *(const float4*)(xpack + dst * XDIM + 28);
            x[29] -= dt.y; x[30] -= dt.z; x[31] -= dt.w;
        } else {
#pragma unroll
            for (int i = 0; i < IN_DIM; ++i) x[i] = features[src * IN_DIM + i];
#pragma unroll
            for (int j = 0; j < 3; ++j)
                x[IN_DIM + j] = node[src * 3 + j] - node[dst * 3 + j];
        }

        float acc = 0.0f;
#pragma unroll
        for (int i = 0; i < XDIM; ++i) acc = fmaf(x[i], w[i], acc);
        const float msg = fmaf(acc, inv_std, bprime);

        // order-preserving float->int key (monotone for signed int compare)
        int b = __float_as_int(msg);
        int key = (b < 0) ? (b ^ 0x7FFFFFFF) : b;
        atomicMax(out + dst * OUT_DIM + lane, key);
    }
}

// ---------------------------------------------------------------------------
// Kernel 3: decode keys back to float; INT_MIN sentinel (no edges) -> 0.0
// ---------------------------------------------------------------------------
__global__ void decode_kernel(int* __restrict__ out, int total) {
    int t = blockIdx.x * blockDim.x + threadIdx.x;
    if (t >= total) return;
    int k = out[t];
    float r;
    if (k == INT_MIN) {
        r = 0.0f;
    } else {
        int b = (k < 0) ? (k ^ 0x7FFFFFFF) : k;
        r = __int_as_float(b);
    }
    ((float*)out)[t] = r;
}

// ---------------------------------------------------------------------------
extern "C" void kernel_launch(void* const* d_in, const int* in_sizes, int n_in,
                              void* d_out, int out_size, void* d_ws, size_t ws_size,
                              hipStream_t stream) {
    const float* node     = (const float*)d_in[0];
    const float* features = (const float*)d_in[1];
    const int*   edges    = (const int*)d_in[2];
    const float* weight   = (const float*)d_in[3];
    const float* gamma    = (const float*)d_in[4];
    const float* beta     = (const float*)d_in[5];
    const float* rmean    = (const float*)d_in[6];
    const float* rvar     = (const float*)d_in[7];

    const int n_nodes = in_sizes[0] / 3;
    const int n_edges = in_sizes[2] / 2;
    int* out_i = (int*)d_out;

    // init keys
    const int total4 = out_size / 4;
    init_kernel<<<(total4 + 255) / 256, 256, 0, stream>>>((int4*)out_i, total4);

    const size_t pack_bytes = (size_t)n_nodes * XDIM * sizeof(float);
    const bool packed = ws_size >= pack_bytes;

    // 8192 waves fills 256 CUs x 32 waves
    const int n_waves = 8192;
    const int epw = (n_edges + n_waves - 1) / n_waves;
    const int n_blocks = n_waves / 4;  // 256 threads = 4 waves per block

    if (packed) {
        float* xp = (float*)d_ws;
        pack_kernel<<<(n_nodes * XDIM + 255) / 256, 256, 0, stream>>>(
            features, node, xp, n_nodes);
        edge_kernel<true><<<n_blocks, 256, 0, stream>>>(
            edges, xp, nullptr, nullptr, weight, gamma, beta, rmean, rvar,
            out_i, n_edges, epw);
    } else {
        edge_kernel<false><<<n_blocks, 256, 0, stream>>>(
            edges, nullptr, features, node, weight, gamma, beta, rmean, rvar,
            out_i, n_edges, epw);
    }

    decode_kernel<<<(out_size + 255) / 256, 256, 0, stream>>>(out_i, out_size);
}

// Round 2
// 377.765 us; speedup vs baseline: 1.0144x; 1.0144x over previous
//
#include <hip/hip_runtime.h>
#include <hip/hip_fp16.h>

#define IN_DIM 29
#define XDIM 32
#define OUT_DIM 64
#define BN_EPS 1e-5f

// ===========================================================================
// Sorted-CSR path.
// out[d][o] = max_{src in N(d)} yq[src][o]  +  (beta[o] - a[o]*mean[o] - a[o]*z_d[o])
// where a = gamma/sqrt(var+eps), yq[n][o] = a[o] * (W[o,:] . [feat_n; node_n]),
// z_d[o] = W[o,29:32] . node_d.  Empty segment -> 0.
// ===========================================================================

// --- K1: per-node transform -> fp16 table yq[n][64] -----------------------
__global__ __launch_bounds__(256) void node_transform_kernel(
    const float* __restrict__ features, const float* __restrict__ node,
    const float* __restrict__ weight, const float* __restrict__ gamma,
    const float* __restrict__ rvar,
    __half* __restrict__ yq, int n_nodes, int npw)
{
    const int lane = threadIdx.x & 63;
    const int wave = (blockIdx.x * blockDim.x + threadIdx.x) >> 6;
    int n0 = wave * npw;
    int n1 = n0 + npw; if (n1 > n_nodes) n1 = n_nodes;

    float w[XDIM];
    const float4* wp = (const float4*)(weight + lane * XDIM);
#pragma unroll
    for (int q = 0; q < 8; ++q) {
        float4 v = wp[q];
        w[4*q+0] = v.x; w[4*q+1] = v.y; w[4*q+2] = v.z; w[4*q+3] = v.w;
    }
    const float a = gamma[lane] * __frsqrt_rn(rvar[lane] + BN_EPS);

    for (int n = n0; n < n1; ++n) {
        const float* f = features + (size_t)n * IN_DIM;
        float acc = 0.0f;
#pragma unroll
        for (int i = 0; i < IN_DIM; ++i) acc = fmaf(f[i], w[i], acc);
        const float* nd = node + (size_t)n * 3;
#pragma unroll
        for (int j = 0; j < 3; ++j) acc = fmaf(nd[j], w[IN_DIM + j], acc);
        yq[(size_t)n * OUT_DIM + lane] = __float2half(acc * a);
    }
}

// --- sort machinery: counting sort of edges by dst -------------------------
__global__ void zero_kernel(int* __restrict__ p, int n) {
    int t = blockIdx.x * blockDim.x + threadIdx.x;
    if (t < n) p[t] = 0;
}

__global__ void hist_kernel(const int* __restrict__ edges,
                            int* __restrict__ counts, int n_edges) {
    int stride = gridDim.x * blockDim.x;
    for (int e = blockIdx.x * blockDim.x + threadIdx.x; e < n_edges; e += stride)
        atomicAdd(&counts[edges[2*e]], 1);
}

// block scans 1024 elements (256 thr x 4), writes exclusive prefix + block sum
__global__ __launch_bounds__(256) void scan_a_kernel(
    const int* __restrict__ counts, int n,
    int* __restrict__ excl, int* __restrict__ aux)
{
    const int t = threadIdx.x;
    const int base = blockIdx.x * 1024 + t * 4;
    int v[4];
#pragma unroll
    for (int k = 0; k < 4; ++k) v[k] = (base + k < n) ? counts[base + k] : 0;
    int tsum = v[0] + v[1] + v[2] + v[3];

    const int lane = t & 63, wv = t >> 6;
    int x = tsum;
#pragma unroll
    for (int off = 1; off < 64; off <<= 1) {
        int y = __shfl_up(x, off);
        if (lane >= off) x += y;
    }
    __shared__ int wsum[4];
    if (lane == 63) wsum[wv] = x;
    __syncthreads();
    int wexcl = 0;
    for (int i = 0; i < wv; ++i) wexcl += wsum[i];
    int run = wexcl + x - tsum;   // exclusive prefix for this thread
#pragma unroll
    for (int k = 0; k < 4; ++k) {
        if (base + k < n) excl[base + k] = run;
        run += v[k];
    }
    if (t == 255) aux[blockIdx.x] = run;  // block total
}

__global__ void scan_b_kernel(int* __restrict__ aux, int nb) {
    if (threadIdx.x == 0 && blockIdx.x == 0) {
        int run = 0;
        for (int i = 0; i < nb; ++i) { int t = aux[i]; aux[i] = run; run += t; }
    }
}

__global__ void scan_c_kernel(int* __restrict__ offsets, const int* __restrict__ aux,
                              int* __restrict__ cursor, int n, int n_edges) {
    int t = blockIdx.x * blockDim.x + threadIdx.x;
    if (t < n) {
        int v = offsets[t] + aux[t >> 10];
        offsets[t] = v;
        cursor[t] = v;
    }
    if (t == 0) offsets[n] = n_edges;
}

__global__ void scatter_kernel(const int* __restrict__ edges,
                               int* __restrict__ cursor,
                               int* __restrict__ sorted_src, int n_edges) {
    int stride = gridDim.x * blockDim.x;
    for (int e = blockIdx.x * blockDim.x + threadIdx.x; e < n_edges; e += stride) {
        int dst = edges[2*e], src = edges[2*e+1];
        int p = atomicAdd(&cursor[dst], 1);
        sorted_src[p] = src;
    }
}

// --- K2: per-node max-pool over sorted neighbors ---------------------------
__global__ __launch_bounds__(256) void pool_kernel(
    const int* __restrict__ offsets, const int* __restrict__ sorted_src,
    const __half* __restrict__ yq, const float* __restrict__ node,
    const float* __restrict__ weight, const float* __restrict__ gamma,
    const float* __restrict__ beta, const float* __restrict__ rmean,
    const float* __restrict__ rvar,
    float* __restrict__ out, int n_nodes, int npw)
{
    const int lane = threadIdx.x & 63;
    const int wave = (blockIdx.x * blockDim.x + threadIdx.x) >> 6;
    int n0 = wave * npw;
    int n1 = n0 + npw; if (n1 > n_nodes) n1 = n_nodes;

    const float a = gamma[lane] * __frsqrt_rn(rvar[lane] + BN_EPS);
    const float bprime = beta[lane] - rmean[lane] * a;
    const float w29 = weight[lane * XDIM + 29] * a;
    const float w30 = weight[lane * XDIM + 30] * a;
    const float w31 = weight[lane * XDIM + 31] * a;

    for (int d = n0; d < n1; ++d) {
        const int beg = offsets[d], end = offsets[d + 1];
        float acc = -INFINITY;
        int j = beg;
        for (; j + 4 <= end; j += 4) {
            int s0 = sorted_src[j+0], s1 = sorted_src[j+1];
            int s2 = sorted_src[j+2], s3 = sorted_src[j+3];
            float v0 = __half2float(yq[(size_t)s0 * OUT_DIM + lane]);
            float v1 = __half2float(yq[(size_t)s1 * OUT_DIM + lane]);
            float v2 = __half2float(yq[(size_t)s2 * OUT_DIM + lane]);
            float v3 = __half2float(yq[(size_t)s3 * OUT_DIM + lane]);
            acc = fmaxf(acc, fmaxf(fmaxf(v0, v1), fmaxf(v2, v3)));
        }
        for (; j < end; ++j) {
            int s = sorted_src[j];
            acc = fmaxf(acc, __half2float(yq[(size_t)s * OUT_DIM + lane]));
        }
        float r;
        if (beg == end) {
            r = 0.0f;
        } else {
            float nx = node[(size_t)d*3+0], ny = node[(size_t)d*3+1], nz = node[(size_t)d*3+2];
            float c = bprime - (w29 * nx + w30 * ny + w31 * nz);
            r = acc + c;
        }
        out[(size_t)d * OUT_DIM + lane] = r;
    }
}

// ===========================================================================
// Fallback path (no workspace): round-1 direct atomic kernels
// ===========================================================================
__global__ void init_kernel(int4* __restrict__ out, int total4) {
    int t = blockIdx.x * blockDim.x + threadIdx.x;
    if (t < total4) out[t] = make_int4(INT_MIN, INT_MIN, INT_MIN, INT_MIN);
}

__global__ __launch_bounds__(256) void edge_atomic_kernel(
    const int* __restrict__ edges,
    const float* __restrict__ features, const float* __restrict__ node,
    const float* __restrict__ weight, const float* __restrict__ gamma,
    const float* __restrict__ beta, const float* __restrict__ rmean,
    const float* __restrict__ rvar,
    int* __restrict__ out, int n_edges, int epw)
{
    const int lane = threadIdx.x & 63;
    const int wave = (blockIdx.x * blockDim.x + threadIdx.x) >> 6;
    int e0 = wave * epw, e1 = e0 + epw;
    if (e1 > n_edges) e1 = n_edges;

    float w[XDIM];
    const float4* wp = (const float4*)(weight + lane * XDIM);
#pragma unroll
    for (int q = 0; q < 8; ++q) {
        float4 v = wp[q];
        w[4*q+0] = v.x; w[4*q+1] = v.y; w[4*q+2] = v.z; w[4*q+3] = v.w;
    }
    const float a = gamma[lane] * __frsqrt_rn(rvar[lane] + BN_EPS);
    const float bprime = beta[lane] - rmean[lane] * a;

    for (int e = e0; e < e1; ++e) {
        const int dst = edges[2*e+0], src = edges[2*e+1];
        float x[XDIM];
#pragma unroll
        for (int i = 0; i < IN_DIM; ++i) x[i] = features[(size_t)src * IN_DIM + i];
#pragma unroll
        for (int j = 0; j < 3; ++j)
            x[IN_DIM+j] = node[(size_t)src*3+j] - node[(size_t)dst*3+j];
        float acc = 0.0f;
#pragma unroll
        for (int i = 0; i < XDIM; ++i) acc = fmaf(x[i], w[i], acc);
        float msg = fmaf(acc, a, bprime);
        int b = __float_as_int(msg);
        int key = (b < 0) ? (b ^ 0x7FFFFFFF) : b;
        atomicMax(out + (size_t)dst * OUT_DIM + lane, key);
    }
}

__global__ void decode_kernel(int* __restrict__ out, int total) {
    int t = blockIdx.x * blockDim.x + threadIdx.x;
    if (t >= total) return;
    int k = out[t];
    float r;
    if (k == INT_MIN) r = 0.0f;
    else { int b = (k < 0) ? (k ^ 0x7FFFFFFF) : k; r = __int_as_float(b); }
    ((float*)out)[t] = r;
}

// ===========================================================================
extern "C" void kernel_launch(void* const* d_in, const int* in_sizes, int n_in,
                              void* d_out, int out_size, void* d_ws, size_t ws_size,
                              hipStream_t stream) {
    const float* node     = (const float*)d_in[0];
    const float* features = (const float*)d_in[1];
    const int*   edges    = (const int*)d_in[2];
    const float* weight   = (const float*)d_in[3];
    const float* gamma    = (const float*)d_in[4];
    const float* beta     = (const float*)d_in[5];
    const float* rmean    = (const float*)d_in[6];
    const float* rvar     = (const float*)d_in[7];

    const int n_nodes = in_sizes[0] / 3;
    const int n_edges = in_sizes[2] / 2;
    const int nb1 = (n_nodes + 1023) / 1024;

    // workspace layout
    size_t off = 0;
    auto alloc = [&](size_t bytes) { size_t r = off; off = (off + bytes + 15) & ~(size_t)15; return r; };
    size_t o_yq     = alloc((size_t)n_nodes * OUT_DIM * sizeof(__half));
    size_t o_counts = alloc((size_t)n_nodes * sizeof(int));
    size_t o_offs   = alloc((size_t)(n_nodes + 1) * sizeof(int));
    size_t o_cursor = alloc((size_t)n_nodes * sizeof(int));
    size_t o_aux    = alloc((size_t)nb1 * sizeof(int));
    size_t o_sorted = alloc((size_t)n_edges * sizeof(int));
    const size_t need = off;

    const int n_waves = 8192;
    const int npw = (n_nodes + n_waves - 1) / n_waves;

    if (ws_size >= need) {
        char* base  = (char*)d_ws;
        __half* yq  = (__half*)(base + o_yq);
        int* counts = (int*)(base + o_counts);
        int* offs   = (int*)(base + o_offs);
        int* cursor = (int*)(base + o_cursor);
        int* aux    = (int*)(base + o_aux);
        int* sorted = (int*)(base + o_sorted);

        zero_kernel<<<(n_nodes + 255) / 256, 256, 0, stream>>>(counts, n_nodes);
        node_transform_kernel<<<n_waves / 4, 256, 0, stream>>>(
            features, node, weight, gamma, rvar, yq, n_nodes, npw);
        hist_kernel<<<1024, 256, 0, stream>>>(edges, counts, n_edges);
        scan_a_kernel<<<nb1, 256, 0, stream>>>(counts, n_nodes, offs, aux);
        scan_b_kernel<<<1, 64, 0, stream>>>(aux, nb1);
        scan_c_kernel<<<(n_nodes + 255) / 256, 256, 0, stream>>>(
            offs, aux, cursor, n_nodes, n_edges);
        scatter_kernel<<<1024, 256, 0, stream>>>(edges, cursor, sorted, n_edges);
        pool_kernel<<<n_waves / 4, 256, 0, stream>>>(
            offs, sorted, yq, node, weight, gamma, beta, rmean, rvar,
            (float*)d_out, n_nodes, npw);
    } else {
        int* out_i = (int*)d_out;
        const int total4 = out_size / 4;
        init_kernel<<<(total4 + 255) / 256, 256, 0, stream>>>((int4*)out_i, total4);
        const int epw = (n_edges + n_waves - 1) / n_waves;
        edge_atomic_kernel<<<n_waves / 4, 256, 0, stream>>>(
            edges, features, node, weight, gamma, beta, rmean, rvar,
            out_i, n_edges, epw);
        decode_kernel<<<(out_size + 255) / 256, 256, 0, stream>>>(out_i, out_size);
    }
}